// Round 1
// baseline (857.213 us; speedup 1.0000x reference)
//
#include <hip/hip_runtime.h>
#include <hip/hip_bf16.h>

#define NREF  4096
#define NTR   8192
#define NCOMB 12288
#define DIN   384
#define HID   1024
#define NE    4

// ---------------------------------------------------------------------------
// ws layout (bytes):
//   0      : cnt[4]    (combined per-element row counts)
//   16     : rcnt[4]   (ref-only per-element counts)
//   256    : comb[4*12288] int  (combined row ids, grouped by element)
//   196864 : ridx[4*4096]  int  (ref row ids, grouped by element)
//   524288 : H1[12288*1024] f32 (celu(layer1) activations, indexed by row id)
//   524288+50331648 : hfin[12288] f32 (final scalar embedding per row)
// total ~50.9 MB
// ---------------------------------------------------------------------------

__global__ void k_compact(const int* __restrict__ lr, const int* __restrict__ lt,
                          int* cnt, int* rcnt, int* comb, int* ridx) {
    int i = blockIdx.x * 256 + threadIdx.x;
    if (i < NREF) {
        int e = lr[i] - 1;
        int p = atomicAdd(&rcnt[e], 1);
        ridx[e * NREF + p] = i;
        int q = atomicAdd(&cnt[e], 1);
        comb[e * NCOMB + q] = i;
    } else if (i < NCOMB) {
        int t = i - NREF;
        int e = lt[t] - 1;
        int q = atomicAdd(&cnt[e], 1);
        comb[e * NCOMB + q] = NREF + t;
    }
}

// Layer 1: H1[g] = celu(x[g] @ W1[e] + b1[e]),  x row gathered via comb list.
__global__ __launch_bounds__(256) void k_l1(
    const float* __restrict__ xr, const float* __restrict__ xt,
    const float* __restrict__ W1, const float* __restrict__ b1,
    const int* __restrict__ cnt, const int* __restrict__ comb,
    float* __restrict__ H1) {
    int e = blockIdx.z;
    int count = cnt[e];
    int m0 = blockIdx.x * 64;
    if (m0 >= count) return;
    int n0 = blockIdx.y * 64;

    __shared__ float As[64][17];
    __shared__ float Bs[16][64];

    int tid = threadIdx.x;
    int tx = tid & 15, ty = tid >> 4;
    const int* lst = comb + e * NCOMB;

    int rowA = tid >> 2, kA = (tid & 3) * 4;
    int mA = m0 + rowA; if (mA >= count) mA = count - 1;
    int gA = lst[mA];
    const float* xsrc = (gA < NREF) ? (xr + (size_t)gA * DIN)
                                    : (xt + (size_t)(gA - NREF) * DIN);
    const float* Wsrc = W1 + (size_t)e * DIN * HID;

    float acc[4][4] = {};
    for (int k0 = 0; k0 < DIN; k0 += 16) {
        float4 av = *(const float4*)(xsrc + k0 + kA);
        As[rowA][kA + 0] = av.x; As[rowA][kA + 1] = av.y;
        As[rowA][kA + 2] = av.z; As[rowA][kA + 3] = av.w;
        float4 bv = *(const float4*)(Wsrc + (size_t)(k0 + ty) * HID + n0 + tx * 4);
        *(float4*)&Bs[ty][tx * 4] = bv;
        __syncthreads();
#pragma unroll
        for (int k = 0; k < 16; k++) {
            float a[4], b[4];
#pragma unroll
            for (int i = 0; i < 4; i++) a[i] = As[ty * 4 + i][k];
#pragma unroll
            for (int j = 0; j < 4; j++) b[j] = Bs[k][tx * 4 + j];
#pragma unroll
            for (int i = 0; i < 4; i++)
#pragma unroll
                for (int j = 0; j < 4; j++) acc[i][j] += a[i] * b[j];
        }
        __syncthreads();
    }
#pragma unroll
    for (int i = 0; i < 4; i++) {
        int m = m0 + ty * 4 + i;
        if (m < count) {
            int g = lst[m];
            float* dst = H1 + (size_t)g * HID + n0 + tx * 4;
#pragma unroll
            for (int j = 0; j < 4; j++) {
                float v = acc[i][j] + b1[e * HID + n0 + tx * 4 + j];
                v = v > 0.f ? v : (expf(v) - 1.f);   // celu, alpha=1
                dst[j] = v;
            }
        }
    }
}

// Layers 2+3 fused: hfin[g] += sum_j celu(H1[g]@W2[:,j]+b2[j]) * W3[j]
// (b3 omitted: it cancels in |ht - hr|)
__global__ __launch_bounds__(256) void k_l23(
    const float* __restrict__ H1, const float* __restrict__ W2,
    const float* __restrict__ b2, const float* __restrict__ W3,
    const int* __restrict__ cnt, const int* __restrict__ comb,
    float* __restrict__ hfin) {
    int e = blockIdx.z;
    int count = cnt[e];
    int m0 = blockIdx.x * 64;
    if (m0 >= count) return;
    int n0 = blockIdx.y * 64;

    __shared__ float As[64][17];
    __shared__ float Bs[16][64];

    int tid = threadIdx.x;
    int tx = tid & 15, ty = tid >> 4;
    const int* lst = comb + e * NCOMB;

    int rowA = tid >> 2, kA = (tid & 3) * 4;
    int mA = m0 + rowA; if (mA >= count) mA = count - 1;
    int gA = lst[mA];
    const float* xsrc = H1 + (size_t)gA * HID;
    const float* Wsrc = W2 + (size_t)e * HID * HID;

    float acc[4][4] = {};
    for (int k0 = 0; k0 < HID; k0 += 16) {
        float4 av = *(const float4*)(xsrc + k0 + kA);
        As[rowA][kA + 0] = av.x; As[rowA][kA + 1] = av.y;
        As[rowA][kA + 2] = av.z; As[rowA][kA + 3] = av.w;
        float4 bv = *(const float4*)(Wsrc + (size_t)(k0 + ty) * HID + n0 + tx * 4);
        *(float4*)&Bs[ty][tx * 4] = bv;
        __syncthreads();
#pragma unroll
        for (int k = 0; k < 16; k++) {
            float a[4], b[4];
#pragma unroll
            for (int i = 0; i < 4; i++) a[i] = As[ty * 4 + i][k];
#pragma unroll
            for (int j = 0; j < 4; j++) b[j] = Bs[k][tx * 4 + j];
#pragma unroll
            for (int i = 0; i < 4; i++)
#pragma unroll
                for (int j = 0; j < 4; j++) acc[i][j] += a[i] * b[j];
        }
        __syncthreads();
    }
    // epilogue: celu + weight by W3, reduce over the 64 cols of this tile
    float s[4] = {0.f, 0.f, 0.f, 0.f};
#pragma unroll
    for (int j = 0; j < 4; j++) {
        int col = n0 + tx * 4 + j;
        float bb = b2[e * HID + col];
        float w3 = W3[e * HID + col];
#pragma unroll
        for (int i = 0; i < 4; i++) {
            float v = acc[i][j] + bb;
            v = v > 0.f ? v : (expf(v) - 1.f);
            s[i] += v * w3;
        }
    }
#pragma unroll
    for (int i = 0; i < 4; i++) {
#pragma unroll
        for (int o = 8; o > 0; o >>= 1) s[i] += __shfl_xor(s[i], o, 16);
    }
    if (tx == 0) {
#pragma unroll
        for (int i = 0; i < 4; i++) {
            int m = m0 + ty * 4 + i;
            if (m < count) atomicAdd(&hfin[lst[m]], s[i]);
        }
    }
}

// Final: per train atom, exp-kernel weighted average of y_ref over its element's refs.
__global__ __launch_bounds__(256) void k_out(
    const int* __restrict__ lt, const float* __restrict__ yref,
    const float* __restrict__ alpha, const int* __restrict__ rcnt,
    const int* __restrict__ ridx, const float* __restrict__ hfin,
    float* __restrict__ out) {
    int t = blockIdx.x * 4 + (threadIdx.x >> 6);
    int lane = threadIdx.x & 63;
    if (t >= NTR) return;
    int lab = lt[t];
    int e = lab - 1;
    float ht = hfin[NREF + t];
    float a = alpha[e];
    int n = rcnt[e];
    const int* lst = ridx + e * NREF;
    float num = 0.f, den = 0.f;
    for (int i = lane; i < n; i += 64) {
        int r = lst[i];
        float d = fabsf(ht - hfin[r]);
        float p = expf(-a * d);
        num += p * yref[r];
        den += p;
    }
#pragma unroll
    for (int o = 32; o > 0; o >>= 1) {
        num += __shfl_down(num, o, 64);
        den += __shfl_down(den, o, 64);
    }
    if (lane == 0) {
        out[t] = (float)lab;          // output 0: l_train
        out[NTR + t] = num / den;     // output 1: y
    }
}

extern "C" void kernel_launch(void* const* d_in, const int* in_sizes, int n_in,
                              void* d_out, int out_size, void* d_ws, size_t ws_size,
                              hipStream_t stream) {
    const float* xr    = (const float*)d_in[0];
    const float* yref  = (const float*)d_in[1];
    const int*   lr    = (const int*)  d_in[2];
    const float* xt    = (const float*)d_in[3];
    const int*   lt    = (const int*)  d_in[4];
    const float* W1    = (const float*)d_in[5];
    const float* b1    = (const float*)d_in[6];
    const float* W2    = (const float*)d_in[7];
    const float* b2    = (const float*)d_in[8];
    const float* W3    = (const float*)d_in[9];
    // d_in[10] = b3 (cancels in the distance), d_in[11] = alpha
    const float* alpha = (const float*)d_in[11];

    char* ws = (char*)d_ws;
    int*   cnt  = (int*)(ws);
    int*   rcnt = (int*)(ws + 16);
    int*   comb = (int*)(ws + 256);
    int*   ridx = (int*)(ws + 256 + (size_t)NE * NCOMB * 4);
    float* H1   = (float*)(ws + (1 << 19));
    float* hfin = (float*)(ws + (1 << 19) + (size_t)NCOMB * HID * 4);
    float* out  = (float*)d_out;

    hipMemsetAsync(ws, 0, 32, stream);                 // cnt + rcnt
    hipMemsetAsync(hfin, 0, NCOMB * 4, stream);        // embedding accumulators

    k_compact<<<NCOMB / 256, 256, 0, stream>>>(lr, lt, cnt, rcnt, comb, ridx);

    dim3 g1(NCOMB / 64, HID / 64, NE);
    k_l1 <<<g1, 256, 0, stream>>>(xr, xt, W1, b1, cnt, comb, H1);
    k_l23<<<g1, 256, 0, stream>>>(H1, W2, b2, W3, cnt, comb, hfin);

    k_out<<<NTR / 4, 256, 0, stream>>>(lt, yref, alpha, rcnt, ridx, hfin, out);
}

// Round 3
// 388.288 us; speedup vs baseline: 2.2077x; 2.2077x over previous
//
#include <hip/hip_runtime.h>
#include <hip/hip_bf16.h>

#define NREF  4096
#define NTR   8192
#define NCOMB 12288
#define DIN   384
#define HID   1024
#define NE    4

typedef __attribute__((ext_vector_type(8))) short bf16x8;
typedef __attribute__((ext_vector_type(4))) float f32x4;

// ---------------------------------------------------------------------------
// ws layout (bytes)
#define WS_CNT    0
#define WS_RCNT   16
#define WS_COMB   256
#define WS_RIDX   (WS_COMB + 4*NCOMB*4)          // 196864
#define WS_W1TH   (1 << 19)                       // 524288
#define WS_W1TL   (WS_W1TH + NE*HID*DIN*2)        // +3145728
#define WS_W2TH   (WS_W1TL + NE*HID*DIN*2)
#define WS_W2TL   (WS_W2TH + NE*HID*HID*2)        // +8388608
#define WS_H1H    (WS_W2TL + NE*HID*HID*2)
#define WS_H1L    (WS_H1H + (size_t)NCOMB*HID*2)  // +25165824
#define WS_HFIN   (WS_H1L + (size_t)NCOMB*HID*2)
// total ~74 MB
// ---------------------------------------------------------------------------

__device__ __forceinline__ short f2bf(float f) {
    unsigned u = __builtin_bit_cast(unsigned, f);
    unsigned r = (u + 0x7FFF + ((u >> 16) & 1)) >> 16;   // RNE
    return (short)r;
}
__device__ __forceinline__ float bf2f(short s) {
    unsigned u = ((unsigned)(unsigned short)s) << 16;
    return __builtin_bit_cast(float, u);
}
__device__ __forceinline__ void gload16(const void* g, void* l) {
    __builtin_amdgcn_global_load_lds(
        (const __attribute__((address_space(1))) void*)g,
        (__attribute__((address_space(3))) void*)l, 16, 0, 0);
}
__device__ __forceinline__ float celu1(float v) {
    return v > 0.f ? v : (expf(v) - 1.f);
}

__global__ void k_compact(const int* __restrict__ lr, const int* __restrict__ lt,
                          int* cnt, int* rcnt, int* comb, int* ridx) {
    int i = blockIdx.x * 256 + threadIdx.x;
    if (i < NREF) {
        int e = lr[i] - 1;
        int p = atomicAdd(&rcnt[e], 1);
        ridx[e * NREF + p] = i;
        int q = atomicAdd(&cnt[e], 1);
        comb[e * NCOMB + q] = i;
    } else if (i < NCOMB) {
        int t = i - NREF;
        int e = lt[t] - 1;
        int q = atomicAdd(&cnt[e], 1);
        comb[e * NCOMB + q] = NREF + t;
    }
}

// Transpose + hi/lo split: W [e][K][N] f32 -> Th/Tl [e][N][K] bf16
__global__ __launch_bounds__(256) void k_tr(const float* __restrict__ W,
                                            short* __restrict__ Th,
                                            short* __restrict__ Tl,
                                            int K, int N) {
    int e = blockIdx.z;
    __shared__ float s[32][33];
    int tx = threadIdx.x & 31, ty = threadIdx.x >> 5;
    int k0 = blockIdx.y * 32, n0 = blockIdx.x * 32;
    const float* src = W + (size_t)e * K * N;
#pragma unroll
    for (int i = 0; i < 32; i += 8)
        s[ty + i][tx] = src[(size_t)(k0 + ty + i) * N + n0 + tx];
    __syncthreads();
#pragma unroll
    for (int i = 0; i < 32; i += 8) {
        float v = s[tx][ty + i];
        short hb = f2bf(v);
        short lb = f2bf(v - bf2f(hb));
        size_t o = ((size_t)e * N + n0 + ty + i) * K + k0 + tx;
        Th[o] = hb;
        Tl[o] = lb;
    }
}

// ---------------------------------------------------------------------------
// Layer 1: H1[g] = celu(x[g] @ W1[e] + b1[e]); split-bf16 MFMA, A reg-staged.
// Tile 128x128, BK=32, 4 waves (2x2 of 64x64), 16x16x32 bf16 MFMA x3 (hi/lo).
__global__ __launch_bounds__(256) void k_l1(
    const float* __restrict__ xr, const float* __restrict__ xt,
    const short* __restrict__ W1Th, const short* __restrict__ W1Tl,
    const float* __restrict__ b1,
    const int* __restrict__ cnt, const int* __restrict__ comb,
    short* __restrict__ H1h, short* __restrict__ H1l) {
    int e = blockIdx.z;
    int count = cnt[e];
    int m0 = blockIdx.x * 128;
    if (m0 >= count) return;
    int n0 = blockIdx.y * 128;
    const int* lst = comb + e * NCOMB;

    __shared__ __align__(16) char smem[32768];
    // A_hi [128][32] @0, A_lo @8192, B_hi @16384, B_lo @24576 (swizzled cb)

    int t = threadIdx.x;
    int w = t >> 6, lane = t & 63;
    int wr = w >> 1, wc = w & 1;

    // A staging (reg): thread t -> row ar = t>>1, half h = t&1 (16 f32)
    int ar = t >> 1, ha = t & 1;
    int arow = m0 + ar; if (arow >= count) arow = count - 1;
    int gA = lst[arow];
    const float* xsrc = (gA < NREF) ? (xr + (size_t)gA * DIN)
                                    : (xt + (size_t)(gA - NREF) * DIN);
    int fA = (ar >> 1) & 3;
    int woff0 = ar * 64 + (((ha * 2 + 0) ^ fA) << 4);
    int woff1 = ar * 64 + (((ha * 2 + 1) ^ fA) << 4);

    // B staging (global_load_lds): chunk c: row c*64 + (t>>2), slot x = t&3
    int srow = t >> 2, sx = t & 3;
    int fB = (srow >> 1) & 3;
    size_t boff0 = ((size_t)e * HID + n0 + srow) * DIN + ((sx ^ fB) * 8);
    size_t boff1 = ((size_t)e * HID + n0 + 64 + srow) * DIN + ((sx ^ fB) * 8);
    char* ldsB = smem + 16384 + w * 1024;   // wave-uniform; HW adds lane*16

    f32x4 acc[4][4] = {};

    for (int k0 = 0; k0 < DIN; k0 += 32) {
        // B: 4 wave-issues (hi c0, hi c1, lo c0, lo c1)
        gload16(W1Th + boff0 + k0, ldsB + 0);
        gload16(W1Th + boff1 + k0, ldsB + 4096);
        gload16(W1Tl + boff0 + k0, ldsB + 8192);
        gload16(W1Tl + boff1 + k0, ldsB + 12288);
        // A: load 16 f32, split, ds_write swizzled
        float4 v0 = *(const float4*)(xsrc + k0 + ha * 16);
        float4 v1 = *(const float4*)(xsrc + k0 + ha * 16 + 4);
        float4 v2 = *(const float4*)(xsrc + k0 + ha * 16 + 8);
        float4 v3 = *(const float4*)(xsrc + k0 + ha * 16 + 12);
        float fv[16] = {v0.x, v0.y, v0.z, v0.w, v1.x, v1.y, v1.z, v1.w,
                        v2.x, v2.y, v2.z, v2.w, v3.x, v3.y, v3.z, v3.w};
        short hb[16], lb[16];
#pragma unroll
        for (int i = 0; i < 16; i++) {
            hb[i] = f2bf(fv[i]);
            lb[i] = f2bf(fv[i] - bf2f(hb[i]));
        }
        bf16x8 hv0, hv1, lv0, lv1;
#pragma unroll
        for (int i = 0; i < 8; i++) {
            hv0[i] = hb[i]; hv1[i] = hb[8 + i];
            lv0[i] = lb[i]; lv1[i] = lb[8 + i];
        }
        *(bf16x8*)(smem + woff0) = hv0;
        *(bf16x8*)(smem + woff1) = hv1;
        *(bf16x8*)(smem + 8192 + woff0) = lv0;
        *(bf16x8*)(smem + 8192 + woff1) = lv1;
        __syncthreads();

        bf16x8 ah[4], al[4], bh[4], bl[4];
#pragma unroll
        for (int m = 0; m < 4; m++) {
            int row = wr * 64 + m * 16 + (lane & 15);
            int off = row * 64 + ((((lane >> 4) ^ ((row >> 1) & 3))) << 4);
            ah[m] = *(const bf16x8*)(smem + off);
            al[m] = *(const bf16x8*)(smem + 8192 + off);
        }
#pragma unroll
        for (int n = 0; n < 4; n++) {
            int row = wc * 64 + n * 16 + (lane & 15);
            int off = row * 64 + ((((lane >> 4) ^ ((row >> 1) & 3))) << 4);
            bh[n] = *(const bf16x8*)(smem + 16384 + off);
            bl[n] = *(const bf16x8*)(smem + 24576 + off);
        }
#pragma unroll
        for (int m = 0; m < 4; m++)
#pragma unroll
            for (int n = 0; n < 4; n++) {
                acc[m][n] = __builtin_amdgcn_mfma_f32_16x16x32_bf16(ah[m], bh[n], acc[m][n], 0, 0, 0);
                acc[m][n] = __builtin_amdgcn_mfma_f32_16x16x32_bf16(al[m], bh[n], acc[m][n], 0, 0, 0);
                acc[m][n] = __builtin_amdgcn_mfma_f32_16x16x32_bf16(ah[m], bl[n], acc[m][n], 0, 0, 0);
            }
        __syncthreads();
    }

    // epilogue: bias + celu, split-store to H1 planes
#pragma unroll
    for (int m = 0; m < 4; m++) {
        int row = m0 + wr * 64 + m * 16 + (lane >> 4) * 4;
#pragma unroll
        for (int r = 0; r < 4; r++) {
            if (row + r < count) {
                int g = lst[row + r];
#pragma unroll
                for (int n = 0; n < 4; n++) {
                    int col = n0 + wc * 64 + n * 16 + (lane & 15);
                    float v = celu1(acc[m][n][r] + b1[e * HID + col]);
                    short hb2 = f2bf(v);
                    short lb2 = f2bf(v - bf2f(hb2));
                    H1h[(size_t)g * HID + col] = hb2;
                    H1l[(size_t)g * HID + col] = lb2;
                }
            }
        }
    }
}

// ---------------------------------------------------------------------------
// Layers 2+3 fused: hfin[g] += sum_col celu(H1[g]@W2[:,col]+b2[col]) * W3[col]
__global__ __launch_bounds__(256) void k_l23(
    const short* __restrict__ H1h, const short* __restrict__ H1l,
    const short* __restrict__ W2Th, const short* __restrict__ W2Tl,
    const float* __restrict__ b2, const float* __restrict__ W3,
    const int* __restrict__ cnt, const int* __restrict__ comb,
    float* __restrict__ hfin) {
    int e = blockIdx.z;
    int count = cnt[e];
    int m0 = blockIdx.x * 128;
    if (m0 >= count) return;
    int n0 = blockIdx.y * 128;
    const int* lst = comb + e * NCOMB;

    __shared__ __align__(16) char smem[32768];

    int t = threadIdx.x;
    int w = t >> 6, lane = t & 63;
    int wr = w >> 1, wc = w & 1;

    int srow = t >> 2, sx = t & 3;
    int f0 = (srow >> 1) & 3;
    int arow0 = m0 + srow;      if (arow0 >= count) arow0 = count - 1;
    int arow1 = m0 + 64 + srow; if (arow1 >= count) arow1 = count - 1;
    size_t aoff0 = (size_t)lst[arow0] * HID + ((sx ^ f0) * 8);
    size_t aoff1 = (size_t)lst[arow1] * HID + ((sx ^ f0) * 8);
    size_t boff0 = ((size_t)e * HID + n0 + srow) * HID + ((sx ^ f0) * 8);
    size_t boff1 = ((size_t)e * HID + n0 + 64 + srow) * HID + ((sx ^ f0) * 8);
    char* ldsW = smem + w * 1024;   // wave-uniform base; HW adds lane*16

    f32x4 acc[4][4] = {};

    for (int k0 = 0; k0 < HID; k0 += 32) {
        gload16(H1h + aoff0 + k0, ldsW + 0);
        gload16(H1h + aoff1 + k0, ldsW + 4096);
        gload16(H1l + aoff0 + k0, ldsW + 8192);
        gload16(H1l + aoff1 + k0, ldsW + 12288);
        gload16(W2Th + boff0 + k0, ldsW + 16384);
        gload16(W2Th + boff1 + k0, ldsW + 20480);
        gload16(W2Tl + boff0 + k0, ldsW + 24576);
        gload16(W2Tl + boff1 + k0, ldsW + 28672);
        __syncthreads();

        bf16x8 ah[4], al[4], bh[4], bl[4];
#pragma unroll
        for (int m = 0; m < 4; m++) {
            int row = wr * 64 + m * 16 + (lane & 15);
            int off = row * 64 + ((((lane >> 4) ^ ((row >> 1) & 3))) << 4);
            ah[m] = *(const bf16x8*)(smem + off);
            al[m] = *(const bf16x8*)(smem + 8192 + off);
        }
#pragma unroll
        for (int n = 0; n < 4; n++) {
            int row = wc * 64 + n * 16 + (lane & 15);
            int off = row * 64 + ((((lane >> 4) ^ ((row >> 1) & 3))) << 4);
            bh[n] = *(const bf16x8*)(smem + 16384 + off);
            bl[n] = *(const bf16x8*)(smem + 24576 + off);
        }
#pragma unroll
        for (int m = 0; m < 4; m++)
#pragma unroll
            for (int n = 0; n < 4; n++) {
                acc[m][n] = __builtin_amdgcn_mfma_f32_16x16x32_bf16(ah[m], bh[n], acc[m][n], 0, 0, 0);
                acc[m][n] = __builtin_amdgcn_mfma_f32_16x16x32_bf16(al[m], bh[n], acc[m][n], 0, 0, 0);
                acc[m][n] = __builtin_amdgcn_mfma_f32_16x16x32_bf16(ah[m], bl[n], acc[m][n], 0, 0, 0);
            }
        __syncthreads();
    }

    // epilogue: celu + W3-weight, reduce over 128 cols of this tile
    float s[4][4] = {};   // [m][reg]
#pragma unroll
    for (int n = 0; n < 4; n++) {
        int col = n0 + wc * 64 + n * 16 + (lane & 15);
        float bb = b2[e * HID + col];
        float w3 = W3[e * HID + col];
#pragma unroll
        for (int m = 0; m < 4; m++)
#pragma unroll
            for (int r = 0; r < 4; r++)
                s[m][r] += celu1(acc[m][n][r] + bb) * w3;
    }
#pragma unroll
    for (int m = 0; m < 4; m++)
#pragma unroll
        for (int r = 0; r < 4; r++) {
#pragma unroll
            for (int off = 8; off > 0; off >>= 1)
                s[m][r] += __shfl_xor(s[m][r], off, 64);
        }
    if ((lane & 15) == 0) {
#pragma unroll
        for (int m = 0; m < 4; m++) {
            int row = m0 + wr * 64 + m * 16 + (lane >> 4) * 4;
#pragma unroll
            for (int r = 0; r < 4; r++)
                if (row + r < count) atomicAdd(&hfin[lst[row + r]], s[m][r]);
        }
    }
}

// ---------------------------------------------------------------------------
__global__ __launch_bounds__(256) void k_out(
    const int* __restrict__ lt, const float* __restrict__ yref,
    const float* __restrict__ alpha, const int* __restrict__ rcnt,
    const int* __restrict__ ridx, const float* __restrict__ hfin,
    float* __restrict__ out) {
    int t = blockIdx.x * 4 + (threadIdx.x >> 6);
    int lane = threadIdx.x & 63;
    if (t >= NTR) return;
    int lab = lt[t];
    int e = lab - 1;
    float ht = hfin[NREF + t];
    float a = alpha[e];
    int n = rcnt[e];
    const int* lst = ridx + e * NREF;
    float num = 0.f, den = 0.f;
    for (int i = lane; i < n; i += 64) {
        int r = lst[i];
        float d = fabsf(ht - hfin[r]);
        float p = expf(-a * d);
        num += p * yref[r];
        den += p;
    }
#pragma unroll
    for (int o = 32; o > 0; o >>= 1) {
        num += __shfl_down(num, o, 64);
        den += __shfl_down(den, o, 64);
    }
    if (lane == 0) {
        out[t] = (float)lab;
        out[NTR + t] = num / den;
    }
}

extern "C" void kernel_launch(void* const* d_in, const int* in_sizes, int n_in,
                              void* d_out, int out_size, void* d_ws, size_t ws_size,
                              hipStream_t stream) {
    const float* xr    = (const float*)d_in[0];
    const float* yref  = (const float*)d_in[1];
    const int*   lr    = (const int*)  d_in[2];
    const float* xt    = (const float*)d_in[3];
    const int*   lt    = (const int*)  d_in[4];
    const float* W1    = (const float*)d_in[5];
    const float* b1    = (const float*)d_in[6];
    const float* W2    = (const float*)d_in[7];
    const float* b2    = (const float*)d_in[8];
    const float* W3    = (const float*)d_in[9];
    // d_in[10] = b3 (cancels in |ht-hr|), d_in[11] = alpha
    const float* alpha = (const float*)d_in[11];

    char* ws = (char*)d_ws;
    int*   cnt  = (int*)(ws + WS_CNT);
    int*   rcnt = (int*)(ws + WS_RCNT);
    int*   comb = (int*)(ws + WS_COMB);
    int*   ridx = (int*)(ws + WS_RIDX);
    short* W1Th = (short*)(ws + WS_W1TH);
    short* W1Tl = (short*)(ws + WS_W1TL);
    short* W2Th = (short*)(ws + WS_W2TH);
    short* W2Tl = (short*)(ws + WS_W2TL);
    short* H1h  = (short*)(ws + WS_H1H);
    short* H1l  = (short*)(ws + WS_H1L);
    float* hfin = (float*)(ws + WS_HFIN);
    float* out  = (float*)d_out;

    hipMemsetAsync(ws, 0, 32, stream);              // cnt + rcnt
    hipMemsetAsync(hfin, 0, NCOMB * 4, stream);

    k_compact<<<NCOMB / 256, 256, 0, stream>>>(lr, lt, cnt, rcnt, comb, ridx);

    k_tr<<<dim3(HID / 32, DIN / 32, NE), 256, 0, stream>>>(W1, W1Th, W1Tl, DIN, HID);
    k_tr<<<dim3(HID / 32, HID / 32, NE), 256, 0, stream>>>(W2, W2Th, W2Tl, HID, HID);

    dim3 g1(NCOMB / 128, HID / 128, NE);
    k_l1 <<<g1, 256, 0, stream>>>(xr, xt, W1Th, W1Tl, b1, cnt, comb, H1h, H1l);
    k_l23<<<g1, 256, 0, stream>>>(H1h, H1l, W2Th, W2Tl, b2, W3, cnt, comb, hfin);

    k_out<<<NTR / 4, 256, 0, stream>>>(lt, yref, alpha, rcnt, ridx, hfin, out);
}